// Round 10
// baseline (965.448 us; speedup 1.0000x reference)
//
#include <hip/hip_runtime.h>
#include <stdint.h>

typedef __attribute__((ext_vector_type(8))) _Float16 half8;
typedef __attribute__((ext_vector_type(2))) _Float16 half2v;
typedef __attribute__((ext_vector_type(4))) float floatx4;
typedef __attribute__((ext_vector_type(4))) uint32_t uint4v;

#define KDIM 4096
#define NDIM 11008
#define NKT 64

#define GLOAD_LDS16(gsrc, ldst)                                                        \
  __builtin_amdgcn_global_load_lds(                                                    \
      (const __attribute__((address_space(1))) void*)(gsrc),                           \
      (__attribute__((address_space(3))) void*)(ldst), 16, 0, 0)

static __device__ __forceinline__ uint32_t pkrtz(float a, float b) {
  auto h = __builtin_amdgcn_cvt_pkrtz(a, b);  // exact: values fp16-representable
  return __builtin_bit_cast(uint32_t, h);
}

// int32 of 8 nibbles -> half8 of (q-8)/7.5*s in k-order; exact (q-8) via 0x6400 trick.
static __device__ __forceinline__ half8 dq8(uint32_t q, half2v ssv) {
  half2v off; off[0] = (_Float16)(-1032.0f); off[1] = (_Float16)(-1032.0f);
  const uint32_t a0 = (q & 0x000F000Fu) | 0x64006400u;
  const uint32_t a1 = ((q >> 4) & 0x000F000Fu) | 0x64006400u;
  const uint32_t a2 = ((q >> 8) & 0x000F000Fu) | 0x64006400u;
  const uint32_t a3 = ((q >> 12) & 0x000F000Fu) | 0x64006400u;
  const uint32_t p0 = __builtin_amdgcn_perm(a1, a0, 0x05040100u);
  const uint32_t p1 = __builtin_amdgcn_perm(a3, a2, 0x05040100u);
  const uint32_t p2 = __builtin_amdgcn_perm(a1, a0, 0x07060302u);
  const uint32_t p3 = __builtin_amdgcn_perm(a3, a2, 0x07060302u);
  uint4v u;
  u[0] = __builtin_bit_cast(uint32_t, (__builtin_bit_cast(half2v, p0) + off) * ssv);
  u[1] = __builtin_bit_cast(uint32_t, (__builtin_bit_cast(half2v, p1) + off) * ssv);
  u[2] = __builtin_bit_cast(uint32_t, (__builtin_bit_cast(half2v, p2) + off) * ssv);
  u[3] = __builtin_bit_cast(uint32_t, (__builtin_bit_cast(half2v, p3) + off) * ssv);
  return __builtin_bit_cast(half8, u);
}

// ---------------- prepass 1: fp32 -> fp16 copy of X ----------------
__global__ __launch_bounds__(256)
void l4b_prep(const float* __restrict__ in, _Float16* __restrict__ out, int n8) {
  int i = blockIdx.x * 256 + threadIdx.x;
  if (i < n8) {
    floatx4 v0 = ((const floatx4*)in)[2 * i];
    floatx4 v1 = ((const floatx4*)in)[2 * i + 1];
    uint4v u;
    u[0] = pkrtz(v0[0], v0[1]); u[1] = pkrtz(v0[2], v0[3]);
    u[2] = pkrtz(v1[0], v1[1]); u[3] = pkrtz(v1[2], v1[3]);
    ((uint4v*)out)[i] = u;
  }
}

// ---------------- prepass 2: dequant + transpose PW -> BH[N][K] fp16 ----------------
__global__ __launch_bounds__(256)
void l4b_prepB(const int* __restrict__ PW, const float* __restrict__ SC,
               _Float16* __restrict__ BH) {
  __shared__ alignas(16) _Float16 lt[64 * 64];
  const int t  = threadIdx.x;
  const int nb = NDIM / 64;           // 172
  const int kb = blockIdx.x / nb;     // 0..63
  const int n0 = (blockIdx.x - kb * nb) * 64;
  const int kp0 = kb * 8;
#pragma unroll
  for (int h = 0; h < 2; ++h) {
    const int idx  = t + h * 256;
    const int kp_l = idx >> 6;
    const int n_l  = idx & 63;
    const int kp   = kp0 + kp_l;
    const uint32_t q = (uint32_t)PW[kp * NDIM + n0 + n_l];
    const float    s = SC[(kp >> 4) * NDIM + n0 + n_l];
    const _Float16 ss = (_Float16)(s * (1.0f / 7.5f));
    half2v sv; sv[0] = ss; sv[1] = ss;
    half8 v = dq8(q, sv);
    *(half8*)&lt[n_l * 64 + ((kp_l ^ (n_l & 7)) * 8)] = v;
  }
  __syncthreads();
  const int n_l = t >> 2;
  const int c   = t & 3;
  uint4v o0 = *(uint4v*)&lt[n_l * 64 + (((c * 2) ^ (n_l & 7)) * 8)];
  uint4v o1 = *(uint4v*)&lt[n_l * 64 + (((c * 2 + 1) ^ (n_l & 7)) * 8)];
  _Float16* op = BH + (int64_t)(n0 + n_l) * KDIM + kp0 * 8 + c * 16;
  *(uint4v*)op       = o0;
  *(uint4v*)(op + 8) = o1;
}

// ---- main: 256x256 fp16 GEMM, k-half staggered DMA staging, counted vmcnt (T3+T4) ----
__global__ __launch_bounds__(512, 2)
void l4b_g3(const _Float16* __restrict__ XH,
            const _Float16* __restrict__ BH,
            float* __restrict__ OUT)
{
  // LDS: [buf][khalf] of 256 rows x 32 halves (64B rows = 4 x 16B slots).
  // Slot swizzle: logical slot s at row r lives in phys slot s ^ (r&3) ^ ((r>>2)&3).
  // DMA dest linear; source pre-swizzled (per-lane constant, derivation in notes).
  __shared__ alignas(16) _Float16 la[2][2][256 * 32];  // 64 KB
  __shared__ alignas(16) _Float16 lb[2][2][256 * 32];  // 64 KB

  const int tid  = threadIdx.x;
  const int lane = tid & 63;
  const int wave = tid >> 6;

  // XCD-aware bijective swizzle (grid = 1376 = 8*172)
  const int cpx = (int)gridDim.x >> 3;
  const int wg  = ((int)blockIdx.x & 7) * cpx + ((int)blockIdx.x >> 3);
  const int by  = wg / 43;
  const int bx  = wg - by * 43;
  const int64_t brow = (int64_t)by * 256;
  const int     bcol = bx * 256;

  // 2M x 4N wave grid, wave tile 128x64
  const int wr = (wave >> 2) * 128;
  const int wc = (wave & 3) * 64;
  const int fr = lane & 15;
  const int fq = lane >> 4;

  floatx4 acc[8][4];
#pragma unroll
  for (int i = 0; i < 8; ++i)
#pragma unroll
    for (int j = 0; j < 4; ++j) acc[i][j] = (floatx4)(0.0f);

  // DMA source: inst (j) covers rows wave*32 + j*16 .. +15 of the tile (1 KB linear).
  // Per-lane: row += lane>>2, phys 16B slot = lane&3 -> logical slot:
  const int s_l = (lane & 3) ^ ((lane >> 2) & 3) ^ ((lane >> 4) & 3);
  const _Float16* const asrc =
      XH + (brow + wave * 32 + (lane >> 2)) * (int64_t)KDIM + s_l * 8;
  const _Float16* const bsrc =
      BH + (bcol + wave * 32 + (lane >> 2)) * (int64_t)KDIM + s_l * 8;

  // Fragment reads: logical slot fq at row m -> phys slot (lane-constant):
  const int rslot = fq ^ (fr & 3) ^ ((fr >> 2) & 3);

  // Stage k-half kh of tile t into buffer bf: 4 DMA/wave (A j0,j1, B j0,j1)
#define G3_S(t, kh, bf)                                                    \
  do {                                                                     \
    GLOAD_LDS16(asrc + (t) * 64 + (kh) * 32,                               \
                &la[bf][kh][(wave * 32) * 32]);                            \
    GLOAD_LDS16(asrc + (int64_t)16 * KDIM + (t) * 64 + (kh) * 32,          \
                &la[bf][kh][(wave * 32 + 16) * 32]);                       \
    GLOAD_LDS16(bsrc + (t) * 64 + (kh) * 32,                               \
                &lb[bf][kh][(wave * 32) * 32]);                            \
    GLOAD_LDS16(bsrc + (int64_t)16 * KDIM + (t) * 64 + (kh) * 32,          \
                &lb[bf][kh][(wave * 32 + 16) * 32]);                       \
  } while (0)

#define G3_READ_B4(bf, kh)                                                 \
  _Pragma("unroll") for (int fn_ = 0; fn_ < 4; ++fn_) {                    \
    const int n_ = wc + fn_ * 16 + fr;                                     \
    bfr[fn_] = *(const half8*)&lb[bf][kh][n_ * 32 + rslot * 8];            \
  }

#define G3_READ_A4(bf, kh, g)                                              \
  _Pragma("unroll") for (int fm_ = 0; fm_ < 4; ++fm_) {                    \
    const int m_ = wr + ((g)*4 + fm_) * 16 + fr;                           \
    af[fm_] = *(const half8*)&la[bf][kh][m_ * 32 + rslot * 8];             \
  }

#define G3_MFMA16(g)                                                       \
  _Pragma("unroll") for (int fm_ = 0; fm_ < 4; ++fm_)                      \
  _Pragma("unroll") for (int fn_ = 0; fn_ < 4; ++fn_)                      \
      acc[(g)*4 + fm_][fn_] = __builtin_amdgcn_mfma_f32_16x16x32_f16(      \
          af[fm_], bfr[fn_], acc[(g)*4 + fm_][fn_], 0, 0, 0);

#define G3_SB() __builtin_amdgcn_sched_barrier(0)
#define G3_BAR() __builtin_amdgcn_s_barrier()
#define G3_LGKM0() asm volatile("s_waitcnt lgkmcnt(0)" ::: "memory")

  // Phase: [reads already issued; optional DMA issued] bar; lgkm0; MFMA; [wait]; bar
#define G3_PHASE(g, WAITC)                                                 \
  G3_SB(); G3_BAR(); G3_LGKM0(); G3_SB();                                  \
  __builtin_amdgcn_s_setprio(1);                                           \
  G3_MFMA16(g);                                                            \
  __builtin_amdgcn_s_setprio(0);                                           \
  G3_SB(); WAITC; G3_SB(); G3_BAR(); G3_SB()

#define G3_NOW()
#define G3_VM8() asm volatile("s_waitcnt vmcnt(8)" ::: "memory")
#define G3_VM4() asm volatile("s_waitcnt vmcnt(4)" ::: "memory")
#define G3_VM0() asm volatile("s_waitcnt vmcnt(0)" ::: "memory")

  // ---- prologue: stage tile 0 (both k-halves); wait oldest 4 (kh0) ----
  G3_S(0, 0, 0);
  G3_S(0, 1, 0);
  G3_SB(); G3_VM4(); G3_SB();
  G3_BAR();
  G3_SB();

  // Steady state in-flight FIFO per wave: [S(t,1), S(t+1,0), S(t+1,1)] at end-P2.
  // vmcnt(8) end-P2 retires S(t,1) (needed P3); vmcnt(4) end-P4 retires S(t+1,0).
  for (int kt = 0; kt < NKT - 1; ++kt) {
    const int bf = kt & 1;
    const int nb = bf ^ 1;
    half8 af[4], bfr[4];

    // P1: kh0 q0 | issue S(kt+1, kh0) into other buffer
    G3_READ_B4(bf, 0);
    G3_READ_A4(bf, 0, 0);
    G3_S(kt + 1, 0, nb);
    G3_PHASE(0, G3_NOW());

    // P2: kh0 q1 | issue S(kt+1, kh1) | vmcnt(8) -> S(kt,kh1) landed
    G3_READ_A4(bf, 0, 1);
    G3_S(kt + 1, 1, nb);
    G3_PHASE(1, G3_VM8());

    // P3: kh1 q2
    G3_READ_B4(bf, 1);
    G3_READ_A4(bf, 1, 0);
    G3_PHASE(0, G3_NOW());

    // P4: kh1 q3 | vmcnt(4) -> S(kt+1,kh0) landed for next P1
    G3_READ_A4(bf, 1, 1);
    G3_PHASE(1, G3_VM4());
  }

  // ---- peeled last tile (kt = NKT-1, buffer 1): no staging; drain kh1 at P2 ----
  {
    const int bf = (NKT - 1) & 1;
    half8 af[4], bfr[4];

    G3_READ_B4(bf, 0);
    G3_READ_A4(bf, 0, 0);
    G3_PHASE(0, G3_NOW());

    G3_READ_A4(bf, 0, 1);
    G3_PHASE(1, G3_VM0());

    G3_READ_B4(bf, 1);
    G3_READ_A4(bf, 1, 0);
    G3_PHASE(0, G3_NOW());

    G3_READ_A4(bf, 1, 1);
    G3_SB(); G3_BAR(); G3_LGKM0(); G3_SB();
    __builtin_amdgcn_s_setprio(1);
    G3_MFMA16(1);
    __builtin_amdgcn_s_setprio(0);
    G3_SB();
  }

  // ---- epilogue: C/D map col=lane&15, row=(lane>>4)*4+reg; fp32 out ----
#pragma unroll
  for (int fm = 0; fm < 8; ++fm)
#pragma unroll
    for (int fn = 0; fn < 4; ++fn)
#pragma unroll
      for (int r = 0; r < 4; ++r) {
        const int64_t row = brow + wr + fm * 16 + fq * 4 + r;
        const int     col = bcol + wc + fn * 16 + fr;
        OUT[row * NDIM + col] = acc[fm][fn][r];
      }
}

// ---------------- fallback (fp32-input, no workspace; proven r3 structure) ----------------
__global__ __launch_bounds__(512, 2)
void l4b_fb(const float* __restrict__ X, const int* __restrict__ PW,
            const float* __restrict__ SC, float* __restrict__ OUT)
{
  __shared__ alignas(16) _Float16 fla[2][256 * 64];
  __shared__ alignas(16) _Float16 flb[2][256 * 64];

  const int tid  = threadIdx.x;
  const int lane = tid & 63;
  const int wave = tid >> 6;

  const int cpx = (int)gridDim.x >> 3;
  const int wg  = ((int)blockIdx.x & 7) * cpx + ((int)blockIdx.x >> 3);
  const int by  = wg / 43;
  const int bx  = wg - by * 43;
  const int64_t brow = (int64_t)by * 256;
  const int     bcol = bx * 256;

  const int wr = (wave >> 2) * 128;
  const int wc = (wave & 3) * 64;
  const int fr = lane & 15;
  const int fq = lane >> 4;

  floatx4 acc[8][4];
#pragma unroll
  for (int i = 0; i < 8; ++i)
#pragma unroll
    for (int j = 0; j < 4; ++j) acc[i][j] = (floatx4)(0.0f);

  const int ar = tid >> 1;
  const int ah = tid & 1;
  const float* const aptr = X + (brow + ar) * (int64_t)KDIM + ah * 32;
  const int bc  = tid & 255;
  const int bkq = tid >> 8;
  const int*   const pwcol = PW + bcol + bc;
  const float* const sccol = SC + bcol + bc;

  floatx4 ra[8];
  int     rwf[4];
  float   rsc;

#define F_LOAD_A(t)                                                        \
  do {                                                                     \
    const float* ap = aptr + (t) * 64;                                     \
    _Pragma("unroll") for (int i_ = 0; i_ < 8; ++i_)                       \
        ra[i_] = *(const floatx4*)(ap + i_ * 4);                           \
  } while (0)

#define F_LOAD_B(t)                                                        \
  do {                                                                     \
    const int* pp = pwcol + ((t) * 8 + bkq) * NDIM;                        \
    _Pragma("unroll") for (int j_ = 0; j_ < 4; ++j_)                       \
        rwf[j_] = pp[j_ * 2 * NDIM];                                       \
    rsc = sccol[(int64_t)((t) >> 1) * NDIM];                               \
  } while (0)

#define F_WRITE_A(dst)                                                     \
  do {                                                                     \
    _Pragma("unroll") for (int i2 = 0; i2 < 4; ++i2) {                     \
      uint4v u;                                                            \
      u[0] = pkrtz(ra[2 * i2][0], ra[2 * i2][1]);                          \
      u[1] = pkrtz(ra[2 * i2][2], ra[2 * i2][3]);                          \
      u[2] = pkrtz(ra[2 * i2 + 1][0], ra[2 * i2 + 1][1]);                  \
      u[3] = pkrtz(ra[2 * i2 + 1][2], ra[2 * i2 + 1][3]);                  \
      const int s_ = ah * 4 + i2;                                          \
      *(half8*)&(dst)[ar * 64 + ((s_ ^ (ar & 7)) * 8)] =                   \
          __builtin_bit_cast(half8, u);                                    \
    }                                                                      \
  } while (0)

#define F_WRITE_B(dst)                                                     \
  do {                                                                     \
    const _Float16 ssf = (_Float16)(rsc * (1.0f / 7.5f));                  \
    half2v sv; sv[0] = ssf; sv[1] = ssf;                                   \
    _Pragma("unroll") for (int j_ = 0; j_ < 4; ++j_) {                     \
      half8 v = dq8((uint32_t)rwf[j_], sv);                                \
      const int kp = bkq + 2 * j_;                                         \
      *(half8*)&(dst)[bc * 64 + ((kp ^ (bc & 7)) * 8)] = v;                \
    }                                                                      \
  } while (0)

#define F_MFMA16(fm0)                                                      \
  __builtin_amdgcn_s_barrier();                                            \
  asm volatile("s_waitcnt lgkmcnt(0)" ::: "memory");                       \
  __builtin_amdgcn_sched_barrier(0);                                       \
  __builtin_amdgcn_s_setprio(1);                                           \
  _Pragma("unroll") for (int fm_ = 0; fm_ < 4; ++fm_)                      \
  _Pragma("unroll") for (int fn_ = 0; fn_ < 4; ++fn_)                      \
      acc[(fm0) + fm_][fn_] = __builtin_amdgcn_mfma_f32_16x16x32_f16(      \
          af[fm_], bfr[fn_], acc[(fm0) + fm_][fn_], 0, 0, 0);              \
  __builtin_amdgcn_s_setprio(0);                                           \
  __builtin_amdgcn_sched_barrier(0);                                       \
  __builtin_amdgcn_s_barrier();                                            \
  __builtin_amdgcn_sched_barrier(0);

  F_LOAD_A(0); F_LOAD_B(0);
  F_WRITE_A(fla[0]); F_WRITE_B(flb[0]);
  F_LOAD_A(1); F_LOAD_B(1);
  asm volatile("s_waitcnt lgkmcnt(0)" ::: "memory");
  __builtin_amdgcn_s_barrier();
  __builtin_amdgcn_sched_barrier(0);

  for (int kt = 0; kt < NKT; ++kt) {
    const int buf = kt & 1;
    const _Float16* lap = fla[buf];
    const _Float16* lbp = flb[buf];
    _Float16* const lan = fla[buf ^ 1];
    _Float16* const lbn = flb[buf ^ 1];
    const bool haveW = (kt + 1 < NKT);
    const bool haveL = (kt + 2 < NKT);

    half8 bfr[4], af[4];

#pragma unroll
    for (int fn_ = 0; fn_ < 4; ++fn_) {
      const int n_ = wc + fn_ * 16 + fr;
      bfr[fn_] = *(const half8*)&lbp[n_ * 64 + ((fq ^ (n_ & 7)) * 8)];
    }
#pragma unroll
    for (int fm_ = 0; fm_ < 4; ++fm_) {
      const int m_ = wr + fm_ * 16 + fr;
      af[fm_] = *(const half8*)&lap[m_ * 64 + ((fq ^ (m_ & 7)) * 8)];
    }
    if (haveW) F_WRITE_A(lan);
    F_MFMA16(0);

#pragma unroll
    for (int fm_ = 0; fm_ < 4; ++fm_) {
      const int m_ = wr + (4 + fm_) * 16 + fr;
      af[fm_] = *(const half8*)&lap[m_ * 64 + ((fq ^ (m_ & 7)) * 8)];
    }
    if (haveL) F_LOAD_A(kt + 2);
    F_MFMA16(4);

#pragma unroll
    for (int fn_ = 0; fn_ < 4; ++fn_) {
      const int n_ = wc + fn_ * 16 + fr;
      bfr[fn_] = *(const half8*)&lbp[n_ * 64 + (((4 + fq) ^ (n_ & 7)) * 8)];
    }
#pragma unroll
    for (int fm_ = 0; fm_ < 4; ++fm_) {
      const int m_ = wr + fm_ * 16 + fr;
      af[fm_] = *(const half8*)&lap[m_ * 64 + (((4 + fq) ^ (m_ & 7)) * 8)];
    }
    if (haveW) F_WRITE_B(lbn);
    F_MFMA16(0);

#pragma unroll
    for (int fm_ = 0; fm_ < 4; ++fm_) {
      const int m_ = wr + (4 + fm_) * 16 + fr;
      af[fm_] = *(const half8*)&lap[m_ * 64 + (((4 + fq) ^ (m_ & 7)) * 8)];
    }
    if (haveL) F_LOAD_B(kt + 2);
    F_MFMA16(4);
  }

#pragma unroll
  for (int fm = 0; fm < 8; ++fm)
#pragma unroll
    for (int fn = 0; fn < 4; ++fn)
#pragma unroll
      for (int r = 0; r < 4; ++r) {
        const int64_t row = brow + wr + fm * 16 + fq * 4 + r;
        const int     col = bcol + wc + fn * 16 + fr;
        OUT[row * NDIM + col] = acc[fm][fn][r];
      }
}

extern "C" void kernel_launch(void* const* d_in, const int* in_sizes, int n_in,
                              void* d_out, int out_size, void* d_ws, size_t ws_size,
                              hipStream_t stream) {
  const float* X   = (const float*)d_in[0];
  const int*   PW  = (const int*)d_in[1];
  const float* SC  = (const float*)d_in[2];
  float*       OUT = (float*)d_out;

  const int    M     = in_sizes[0] / KDIM;                 // 8192
  const size_t needH = (size_t)in_sizes[0] * 2;            // 67.1 MB fp16 X
  const size_t needB = (size_t)KDIM * NDIM * 2;            // 90.2 MB fp16 B
  const int    grid  = (M / 256) * (NDIM / 256);           // 1376

  if (ws_size >= needH + needB && (M % 256) == 0) {
    _Float16* XH = (_Float16*)d_ws;
    _Float16* BH = (_Float16*)((char*)d_ws + needH);
    const int n8 = in_sizes[0] / 8;
    l4b_prep<<<(n8 + 255) / 256, 256, 0, stream>>>(X, XH, n8);
    l4b_prepB<<<(KDIM / 64) * (NDIM / 64), 256, 0, stream>>>(PW, SC, BH);
    l4b_g3<<<grid, 512, 0, stream>>>(XH, BH, OUT);
  } else {
    l4b_fb<<<grid, 512, 0, stream>>>(X, PW, SC, OUT);
  }
}

// Round 11
// 894.873 us; speedup vs baseline: 1.0789x; 1.0789x over previous
//
#include <hip/hip_runtime.h>
#include <stdint.h>

typedef __attribute__((ext_vector_type(8))) _Float16 half8;
typedef __attribute__((ext_vector_type(2))) _Float16 half2v;
typedef __attribute__((ext_vector_type(4))) float floatx4;
typedef __attribute__((ext_vector_type(4))) uint32_t uint4v;

#define KDIM 4096
#define NDIM 11008
#define NKT 64

#define GLOAD_LDS16(gsrc, ldst)                                                        \
  __builtin_amdgcn_global_load_lds(                                                    \
      (const __attribute__((address_space(1))) void*)(gsrc),                           \
      (__attribute__((address_space(3))) void*)(ldst), 16, 0, 0)

static __device__ __forceinline__ uint32_t pkrtz(float a, float b) {
  auto h = __builtin_amdgcn_cvt_pkrtz(a, b);  // exact: values fp16-representable
  return __builtin_bit_cast(uint32_t, h);
}

// int32 of 8 nibbles -> half8 of (q-8)/7.5*s in k-order; exact (q-8) via 0x6400 trick.
static __device__ __forceinline__ half8 dq8(uint32_t q, half2v ssv) {
  half2v off; off[0] = (_Float16)(-1032.0f); off[1] = (_Float16)(-1032.0f);
  const uint32_t a0 = (q & 0x000F000Fu) | 0x64006400u;
  const uint32_t a1 = ((q >> 4) & 0x000F000Fu) | 0x64006400u;
  const uint32_t a2 = ((q >> 8) & 0x000F000Fu) | 0x64006400u;
  const uint32_t a3 = ((q >> 12) & 0x000F000Fu) | 0x64006400u;
  const uint32_t p0 = __builtin_amdgcn_perm(a1, a0, 0x05040100u);
  const uint32_t p1 = __builtin_amdgcn_perm(a3, a2, 0x05040100u);
  const uint32_t p2 = __builtin_amdgcn_perm(a1, a0, 0x07060302u);
  const uint32_t p3 = __builtin_amdgcn_perm(a3, a2, 0x07060302u);
  uint4v u;
  u[0] = __builtin_bit_cast(uint32_t, (__builtin_bit_cast(half2v, p0) + off) * ssv);
  u[1] = __builtin_bit_cast(uint32_t, (__builtin_bit_cast(half2v, p1) + off) * ssv);
  u[2] = __builtin_bit_cast(uint32_t, (__builtin_bit_cast(half2v, p2) + off) * ssv);
  u[3] = __builtin_bit_cast(uint32_t, (__builtin_bit_cast(half2v, p3) + off) * ssv);
  return __builtin_bit_cast(half8, u);
}

// ---------------- prepass 1: fp32 -> fp16 copy of X ----------------
__global__ __launch_bounds__(256)
void l4b_prep(const float* __restrict__ in, _Float16* __restrict__ out, int n8) {
  int i = blockIdx.x * 256 + threadIdx.x;
  if (i < n8) {
    floatx4 v0 = ((const floatx4*)in)[2 * i];
    floatx4 v1 = ((const floatx4*)in)[2 * i + 1];
    uint4v u;
    u[0] = pkrtz(v0[0], v0[1]); u[1] = pkrtz(v0[2], v0[3]);
    u[2] = pkrtz(v1[0], v1[1]); u[3] = pkrtz(v1[2], v1[3]);
    ((uint4v*)out)[i] = u;
  }
}

// ---------------- prepass 2: dequant + transpose PW -> BH[N][K] fp16 ----------------
__global__ __launch_bounds__(256)
void l4b_prepB(const int* __restrict__ PW, const float* __restrict__ SC,
               _Float16* __restrict__ BH) {
  __shared__ alignas(16) _Float16 lt[64 * 64];
  const int t  = threadIdx.x;
  const int nb = NDIM / 64;           // 172
  const int kb = blockIdx.x / nb;     // 0..63
  const int n0 = (blockIdx.x - kb * nb) * 64;
  const int kp0 = kb * 8;
#pragma unroll
  for (int h = 0; h < 2; ++h) {
    const int idx  = t + h * 256;
    const int kp_l = idx >> 6;
    const int n_l  = idx & 63;
    const int kp   = kp0 + kp_l;
    const uint32_t q = (uint32_t)PW[kp * NDIM + n0 + n_l];
    const float    s = SC[(kp >> 4) * NDIM + n0 + n_l];
    const _Float16 ss = (_Float16)(s * (1.0f / 7.5f));
    half2v sv; sv[0] = ss; sv[1] = ss;
    half8 v = dq8(q, sv);
    *(half8*)&lt[n_l * 64 + ((kp_l ^ (n_l & 7)) * 8)] = v;
  }
  __syncthreads();
  const int n_l = t >> 2;
  const int c   = t & 3;
  uint4v o0 = *(uint4v*)&lt[n_l * 64 + (((c * 2) ^ (n_l & 7)) * 8)];
  uint4v o1 = *(uint4v*)&lt[n_l * 64 + (((c * 2 + 1) ^ (n_l & 7)) * 8)];
  _Float16* op = BH + (int64_t)(n0 + n_l) * KDIM + kp0 * 8 + c * 16;
  *(uint4v*)op       = o0;
  *(uint4v*)(op + 8) = o1;
}

// ---- main: 256x256 fp16 GEMM, 1 barrier/kt, wave-slip interior, pipelined reads ----
__global__ __launch_bounds__(512, 2)
void l4b_g4(const _Float16* __restrict__ XH,
            const _Float16* __restrict__ BH,
            float* __restrict__ OUT)
{
  // Row = 64 halves = 128B = 8 x 16B slots; phys slot p holds logical slot p ^ (row&7).
  // Both tiles staged by gload_lds DMA: linear dest, pre-swizzled per-lane source.
  __shared__ alignas(16) _Float16 la[2][256 * 64];  // 64 KB
  __shared__ alignas(16) _Float16 lb[2][256 * 64];  // 64 KB

  const int tid  = threadIdx.x;
  const int lane = tid & 63;
  const int wave = tid >> 6;

  // XCD-aware bijective swizzle (grid = 1376 = 8*172)
  const int cpx = (int)gridDim.x >> 3;
  const int wg  = ((int)blockIdx.x & 7) * cpx + ((int)blockIdx.x >> 3);
  const int by  = wg / 43;
  const int bx  = wg - by * 43;
  const int64_t brow = (int64_t)by * 256;
  const int     bcol = bx * 256;

  // 2M x 4N wave grid, wave tile 128x64
  const int wr = (wave >> 2) * 128;
  const int wc = (wave & 3) * 64;
  const int fr = lane & 15;
  const int fq = lane >> 4;

  floatx4 acc[8][4];
#pragma unroll
  for (int i = 0; i < 8; ++i)
#pragma unroll
    for (int j = 0; j < 4; ++j) acc[i][j] = (floatx4)(0.0f);

  // DMA: per wave 4 insts per operand; inst g8 writes rows wave*32+g8*8 .. +7 (1 KB)
  const int arow8 = lane >> 3;
  const int aslot = (lane & 7) ^ arow8;  // pre-swizzled source slot
  const _Float16* const asrc0 =
      XH + (brow + wave * 32 + arow8) * (int64_t)KDIM + aslot * 8;
  const _Float16* const bsrc0 =
      BH + (bcol + wave * 32 + arow8) * (int64_t)KDIM + aslot * 8;

#define DMA_OP(srcb, t, dst)                                               \
  do {                                                                     \
    _Pragma("unroll") for (int g8 = 0; g8 < 4; ++g8)                       \
        GLOAD_LDS16((srcb) + (int64_t)g8 * 8 * KDIM + (t) * 64,            \
                    &(dst)[(wave * 32 + g8 * 8) * 64]);                    \
  } while (0)

#define READ_B4(dstf, src, ksl)                                            \
  _Pragma("unroll") for (int fn_ = 0; fn_ < 4; ++fn_) {                    \
    const int n_ = wc + fn_ * 16 + fr;                                     \
    dstf[fn_] = *(const half8*)&(src)[n_ * 64 + (((ksl) ^ (n_ & 7)) * 8)]; \
  }

#define READ_A4(dstf, src, fm0, ksl)                                       \
  _Pragma("unroll") for (int fm_ = 0; fm_ < 4; ++fm_) {                    \
    const int m_ = wr + ((fm0) + fm_) * 16 + fr;                           \
    dstf[fm_] = *(const half8*)&(src)[m_ * 64 + (((ksl) ^ (m_ & 7)) * 8)]; \
  }

#define MFMA16(fm0, afv, bfv)                                              \
  __builtin_amdgcn_s_setprio(1);                                           \
  _Pragma("unroll") for (int fm_ = 0; fm_ < 4; ++fm_)                      \
  _Pragma("unroll") for (int fn_ = 0; fn_ < 4; ++fn_)                      \
      acc[(fm0) + fm_][fn_] = __builtin_amdgcn_mfma_f32_16x16x32_f16(      \
          afv[fm_], bfv[fn_], acc[(fm0) + fm_][fn_], 0, 0, 0);             \
  __builtin_amdgcn_s_setprio(0);

  // ---- prologue: stage tile 0 ----
  DMA_OP(asrc0, 0, la[0]);
  DMA_OP(bsrc0, 0, lb[0]);
  asm volatile("s_waitcnt vmcnt(0) lgkmcnt(0)" ::: "memory");
  __builtin_amdgcn_s_barrier();
  __builtin_amdgcn_sched_barrier(0);

  for (int kt = 0; kt < NKT; ++kt) {
    const _Float16* lap = la[kt & 1];
    const _Float16* lbp = lb[kt & 1];
    _Float16* const lan = la[(kt & 1) ^ 1];
    _Float16* const lbn = lb[(kt & 1) ^ 1];

    // Issue all next-tile DMA at kt-top: by the end-of-kt vmcnt(0) these are
    // ~a full kt (>= 4000 cyc) old -> the drain is free.
    if (kt + 1 < NKT) {
      DMA_OP(asrc0, kt + 1, lan);
      DMA_OP(bsrc0, kt + 1, lbn);
    }
    __builtin_amdgcn_sched_barrier(0);

    // Interior: no barriers. All reads target lap/lbp (read-only this kt);
    // waves slip phase so one wave's ds_reads overlap another's MFMAs.
    // Reads are issued one MFMA-block ahead; compiler inserts counted lgkm waits.
    half8 b0[4], b1[4], aA[4], aB[4];
    READ_B4(b0, lbp, fq);
    READ_A4(aA, lap, 0, fq);
    READ_A4(aB, lap, 4, fq);
    MFMA16(0, aA, b0);
    READ_B4(b1, lbp, 4 + fq);
    READ_A4(aA, lap, 0, 4 + fq);
    MFMA16(4, aB, b0);
    READ_A4(aB, lap, 4, 4 + fq);
    MFMA16(0, aA, b1);
    MFMA16(4, aB, b1);

    // Single end-of-kt sync: publish tile kt+1, close WAR on the swapped buffer.
    __builtin_amdgcn_sched_barrier(0);
    asm volatile("s_waitcnt vmcnt(0) lgkmcnt(0)" ::: "memory");
    __builtin_amdgcn_s_barrier();
    __builtin_amdgcn_sched_barrier(0);
  }

  // ---- epilogue: C/D map col=lane&15, row=(lane>>4)*4+reg; fp32 out ----
#pragma unroll
  for (int fm = 0; fm < 8; ++fm)
#pragma unroll
    for (int fn = 0; fn < 4; ++fn)
#pragma unroll
      for (int r = 0; r < 4; ++r) {
        const int64_t row = brow + wr + fm * 16 + fq * 4 + r;
        const int     col = bcol + wc + fn * 16 + fr;
        OUT[row * NDIM + col] = acc[fm][fn][r];
      }
}

// ---------------- fallback (fp32-input, no workspace; proven r3 structure) ----------------
__global__ __launch_bounds__(512, 2)
void l4b_fb(const float* __restrict__ X, const int* __restrict__ PW,
            const float* __restrict__ SC, float* __restrict__ OUT)
{
  __shared__ alignas(16) _Float16 fla[2][256 * 64];
  __shared__ alignas(16) _Float16 flb[2][256 * 64];

  const int tid  = threadIdx.x;
  const int lane = tid & 63;
  const int wave = tid >> 6;

  const int cpx = (int)gridDim.x >> 3;
  const int wg  = ((int)blockIdx.x & 7) * cpx + ((int)blockIdx.x >> 3);
  const int by  = wg / 43;
  const int bx  = wg - by * 43;
  const int64_t brow = (int64_t)by * 256;
  const int     bcol = bx * 256;

  const int wr = (wave >> 2) * 128;
  const int wc = (wave & 3) * 64;
  const int fr = lane & 15;
  const int fq = lane >> 4;

  floatx4 acc[8][4];
#pragma unroll
  for (int i = 0; i < 8; ++i)
#pragma unroll
    for (int j = 0; j < 4; ++j) acc[i][j] = (floatx4)(0.0f);

  const int ar = tid >> 1;
  const int ah = tid & 1;
  const float* const aptr = X + (brow + ar) * (int64_t)KDIM + ah * 32;
  const int bc  = tid & 255;
  const int bkq = tid >> 8;
  const int*   const pwcol = PW + bcol + bc;
  const float* const sccol = SC + bcol + bc;

  floatx4 ra[8];
  int     rwf[4];
  float   rsc;

#define F_LOAD_A(t)                                                        \
  do {                                                                     \
    const float* ap = aptr + (t) * 64;                                     \
    _Pragma("unroll") for (int i_ = 0; i_ < 8; ++i_)                       \
        ra[i_] = *(const floatx4*)(ap + i_ * 4);                           \
  } while (0)

#define F_LOAD_B(t)                                                        \
  do {                                                                     \
    const int* pp = pwcol + ((t) * 8 + bkq) * NDIM;                        \
    _Pragma("unroll") for (int j_ = 0; j_ < 4; ++j_)                       \
        rwf[j_] = pp[j_ * 2 * NDIM];                                       \
    rsc = sccol[(int64_t)((t) >> 1) * NDIM];                               \
  } while (0)

#define F_WRITE_A(dst)                                                     \
  do {                                                                     \
    _Pragma("unroll") for (int i2 = 0; i2 < 4; ++i2) {                     \
      uint4v u;                                                            \
      u[0] = pkrtz(ra[2 * i2][0], ra[2 * i2][1]);                          \
      u[1] = pkrtz(ra[2 * i2][2], ra[2 * i2][3]);                          \
      u[2] = pkrtz(ra[2 * i2 + 1][0], ra[2 * i2 + 1][1]);                  \
      u[3] = pkrtz(ra[2 * i2 + 1][2], ra[2 * i2 + 1][3]);                  \
      const int s_ = ah * 4 + i2;                                          \
      *(half8*)&(dst)[ar * 64 + ((s_ ^ (ar & 7)) * 8)] =                   \
          __builtin_bit_cast(half8, u);                                    \
    }                                                                      \
  } while (0)

#define F_WRITE_B(dst)                                                     \
  do {                                                                     \
    const _Float16 ssf = (_Float16)(rsc * (1.0f / 7.5f));                  \
    half2v sv; sv[0] = ssf; sv[1] = ssf;                                   \
    _Pragma("unroll") for (int j_ = 0; j_ < 4; ++j_) {                     \
      half8 v = dq8((uint32_t)rwf[j_], sv);                                \
      const int kp = bkq + 2 * j_;                                         \
      *(half8*)&(dst)[bc * 64 + ((kp ^ (bc & 7)) * 8)] = v;                \
    }                                                                      \
  } while (0)

#define F_MFMA16(fm0)                                                      \
  __builtin_amdgcn_s_barrier();                                            \
  asm volatile("s_waitcnt lgkmcnt(0)" ::: "memory");                       \
  __builtin_amdgcn_sched_barrier(0);                                       \
  __builtin_amdgcn_s_setprio(1);                                           \
  _Pragma("unroll") for (int fm_ = 0; fm_ < 4; ++fm_)                      \
  _Pragma("unroll") for (int fn_ = 0; fn_ < 4; ++fn_)                      \
      acc[(fm0) + fm_][fn_] = __builtin_amdgcn_mfma_f32_16x16x32_f16(      \
          af[fm_], bfr[fn_], acc[(fm0) + fm_][fn_], 0, 0, 0);              \
  __builtin_amdgcn_s_setprio(0);                                           \
  __builtin_amdgcn_sched_barrier(0);                                       \
  __builtin_amdgcn_s_barrier();                                            \
  __builtin_amdgcn_sched_barrier(0);

  F_LOAD_A(0); F_LOAD_B(0);
  F_WRITE_A(fla[0]); F_WRITE_B(flb[0]);
  F_LOAD_A(1); F_LOAD_B(1);
  asm volatile("s_waitcnt lgkmcnt(0)" ::: "memory");
  __builtin_amdgcn_s_barrier();
  __builtin_amdgcn_sched_barrier(0);

  for (int kt = 0; kt < NKT; ++kt) {
    const int buf = kt & 1;
    const _Float16* lap = fla[buf];
    const _Float16* lbp = flb[buf];
    _Float16* const lan = fla[buf ^ 1];
    _Float16* const lbn = flb[buf ^ 1];
    const bool haveW = (kt + 1 < NKT);
    const bool haveL = (kt + 2 < NKT);

    half8 bfr[4], af[4];

#pragma unroll
    for (int fn_ = 0; fn_ < 4; ++fn_) {
      const int n_ = wc + fn_ * 16 + fr;
      bfr[fn_] = *(const half8*)&lbp[n_ * 64 + ((fq ^ (n_ & 7)) * 8)];
    }
#pragma unroll
    for (int fm_ = 0; fm_ < 4; ++fm_) {
      const int m_ = wr + fm_ * 16 + fr;
      af[fm_] = *(const half8*)&lap[m_ * 64 + ((fq ^ (m_ & 7)) * 8)];
    }
    if (haveW) F_WRITE_A(lan);
    F_MFMA16(0);

#pragma unroll
    for (int fm_ = 0; fm_ < 4; ++fm_) {
      const int m_ = wr + (4 + fm_) * 16 + fr;
      af[fm_] = *(const half8*)&lap[m_ * 64 + ((fq ^ (m_ & 7)) * 8)];
    }
    if (haveL) F_LOAD_A(kt + 2);
    F_MFMA16(4);

#pragma unroll
    for (int fn_ = 0; fn_ < 4; ++fn_) {
      const int n_ = wc + fn_ * 16 + fr;
      bfr[fn_] = *(const half8*)&lbp[n_ * 64 + (((4 + fq) ^ (n_ & 7)) * 8)];
    }
#pragma unroll
    for (int fm_ = 0; fm_ < 4; ++fm_) {
      const int m_ = wr + fm_ * 16 + fr;
      af[fm_] = *(const half8*)&lap[m_ * 64 + (((4 + fq) ^ (m_ & 7)) * 8)];
    }
    if (haveW) F_WRITE_B(lbn);
    F_MFMA16(0);

#pragma unroll
    for (int fm_ = 0; fm_ < 4; ++fm_) {
      const int m_ = wr + (4 + fm_) * 16 + fr;
      af[fm_] = *(const half8*)&lap[m_ * 64 + (((4 + fq) ^ (m_ & 7)) * 8)];
    }
    if (haveL) F_LOAD_B(kt + 2);
    F_MFMA16(4);
  }

#pragma unroll
  for (int fm = 0; fm < 8; ++fm)
#pragma unroll
    for (int fn = 0; fn < 4; ++fn)
#pragma unroll
      for (int r = 0; r < 4; ++r) {
        const int64_t row = brow + wr + fm * 16 + fq * 4 + r;
        const int     col = bcol + wc + fn * 16 + fr;
        OUT[row * NDIM + col] = acc[fm][fn][r];
      }
}

extern "C" void kernel_launch(void* const* d_in, const int* in_sizes, int n_in,
                              void* d_out, int out_size, void* d_ws, size_t ws_size,
                              hipStream_t stream) {
  const float* X   = (const float*)d_in[0];
  const int*   PW  = (const int*)d_in[1];
  const float* SC  = (const float*)d_in[2];
  float*       OUT = (float*)d_out;

  const int    M     = in_sizes[0] / KDIM;                 // 8192
  const size_t needH = (size_t)in_sizes[0] * 2;            // 67.1 MB fp16 X
  const size_t needB = (size_t)KDIM * NDIM * 2;            // 90.2 MB fp16 B
  const int    grid  = (M / 256) * (NDIM / 256);           // 1376

  if (ws_size >= needH + needB && (M % 256) == 0) {
    _Float16* XH = (_Float16*)d_ws;
    _Float16* BH = (_Float16*)((char*)d_ws + needH);
    const int n8 = in_sizes[0] / 8;
    l4b_prep<<<(n8 + 255) / 256, 256, 0, stream>>>(X, XH, n8);
    l4b_prepB<<<(KDIM / 64) * (NDIM / 64), 256, 0, stream>>>(PW, SC, BH);
    l4b_g4<<<grid, 512, 0, stream>>>(XH, BH, OUT);
  } else {
    l4b_fb<<<grid, 512, 0, stream>>>(X, PW, SC, OUT);
  }
}